// Round 8
// baseline (232.719 us; speedup 1.0000x reference)
//
#include <hip/hip_runtime.h>
#include <math.h>

#define BATCHES 8192
#define D_IN    400
#define D_OUT   100
#define QD      10
#define KT      64
#define NKT     7                              // 7*64 = 448 >= 400
#define MTILES  7                              // 7*16 = 112 >= 100
#define WFSZ    (NKT * MTILES * 2 * 64 * 8)    // 50176 shorts per plane
#define NW      4                              // waves per block, 2 batches per wave
#define WCH     512                            // shorts per W chunk (64 lanes x 8)
#define QTR     (7 * WCH)                      // 3584 shorts: one plane-quarter
#define XWF     1280                           // floats per wave X region (2 x 640)
#define SMEMF   (NW * XWF + QTR)               // 5120 + 3584 = 8704 floats = 34816 B
#define QRSTR   2176                           // floats per wave in QR carve (4x2176=8704)

using bf16x8 = __attribute__((ext_vector_type(8))) short;
using f32x4  = __attribute__((ext_vector_type(4))) float;

// ---- wave-64 sum via DPP (row_shr + row_bcast), result broadcast via SGPR ----
template <int CTRL>
__device__ __forceinline__ float dpp_add(float x) {
  int s = __builtin_amdgcn_update_dpp(0, __builtin_bit_cast(int, x),
                                      CTRL, 0xF, 0xF, true);
  return x + __builtin_bit_cast(float, s);
}

__device__ __forceinline__ float wsum64(float x) {
  x = dpp_add<0x111>(x);   // row_shr:1
  x = dpp_add<0x112>(x);   // row_shr:2
  x = dpp_add<0x114>(x);   // row_shr:4
  x = dpp_add<0x118>(x);   // row_shr:8
  x = dpp_add<0x142>(x);   // row_bcast:15
  x = dpp_add<0x143>(x);   // row_bcast:31 -> lane63 has total
  return __builtin_bit_cast(float,
      __builtin_amdgcn_readlane(__builtin_bit_cast(int, x), 63));
}

__device__ __forceinline__ float lane_bcast(float x, int lane) {
  return __builtin_bit_cast(float,
      __builtin_amdgcn_readlane(__builtin_bit_cast(int, x), lane));
}

// async global->LDS, 16B per lane: per-lane global src, wave-uniform LDS base
__device__ __forceinline__ void gload_lds16(const void* g, void* l) {
  __builtin_amdgcn_global_load_lds(
      (const __attribute__((address_space(1))) void*)g,
      (__attribute__((address_space(3))) void*)l, 16, 0, 0);
}

// ---------- prep: W (100,400) fp32 -> A-fragment-ordered bf16 hi/lo planes ----
// layout: e = (((kt*7+mt)*2+ks)*64 + lane)*8 + j ; lane = quad*16 + row16
// padded entries (o>=100 or k>=400) written as ZERO (k-pad MUST be zero: the
// fused kernel feeds garbage-but-finite X at padded k and relies on W=0).
__global__ __launch_bounds__(256) void wprep_kernel(const float* __restrict__ W,
                                                    short* __restrict__ wfh,
                                                    short* __restrict__ wfl) {
  const int e = blockIdx.x * 256 + threadIdx.x;
  if (e >= WFSZ) return;
  const int j = e & 7, lane = (e >> 3) & 63, ks = (e >> 9) & 1, mtkt = e >> 10;
  const int kt = mtkt / MTILES, mt = mtkt - kt * MTILES;
  const int o = mt * 16 + (lane & 15);
  const int k = kt * KT + ks * 32 + (lane >> 4) * 8 + j;
  const float w = (o < D_OUT && k < D_IN) ? W[o * D_IN + k] : 0.f;
  __bf16 h = (__bf16)w;
  float hf = (float)h;
  __bf16 l = (__bf16)(w - hf);
  wfh[e] = __builtin_bit_cast(short, h);
  wfl[e] = __builtin_bit_cast(short, l);
}

// ---------- QR pieces (LAPACK sgeqrf convention), rcp-based, wave-private ----
__device__ __forceinline__ void stage_panel(const f32x4* acc, float* stg,
                                            int col, int quad) {
  if (col < QD) {
    #pragma unroll
    for (int mt = 0; mt < MTILES; ++mt)
      #pragma unroll
      for (int rr = 0; rr < 4; ++rr) {
        const int o = mt * 16 + quad * 4 + rr;
        if (o < D_OUT) stg[o * QD + col] = acc[mt][rr];
      }
  }
}

__device__ __forceinline__ void qr_from_stg(float* stg, float* dst, int lane) {
  const int r = lane;
  float a0[QD], a1[QD];
  #pragma unroll
  for (int q = 0; q < QD; ++q) a0[q] = stg[r * QD + q];
  const bool has1 = (r + 64) < D_OUT;
  #pragma unroll
  for (int q = 0; q < QD; ++q) a1[q] = has1 ? stg[(r + 64) * QD + q] : 0.f;

  float v0[QD], v1[QD], tau[QD];
  #pragma unroll
  for (int j = 0; j < QD; ++j) {
    float cj0  = (r >= j) ? a0[j] : 0.f;
    float part = cj0 * cj0 + a1[j] * a1[j];
    float sig  = wsum64(part);
    float alpha = lane_bcast(a0[j], j);
    float nrm  = __builtin_amdgcn_sqrtf(sig);
    float aab  = fabsf(alpha);
    float rn   = __builtin_amdgcn_rcpf(nrm);
    float rd   = __builtin_amdgcn_rcpf(aab + nrm);
    float sgn  = (alpha >= 0.f) ? 1.f : -1.f;
    float tj   = (sig > 0.f) ? (1.f + aab * rn) : 0.f;
    float inv  = (sig > 0.f) ? sgn * rd : 0.f;      // 1/(alpha - beta)
    tau[j] = tj;
    v0[j]  = (r == j) ? 1.f : ((r > j) ? a0[j] * inv : 0.f);
    v1[j]  = a1[j] * inv;
    #pragma unroll
    for (int k = j + 1; k < QD; ++k) {
      float p = v0[j] * a0[k] + v1[j] * a1[k];
      float s = wsum64(p) * tj;
      a0[k] -= s * v0[j];
      a1[k] -= s * v1[j];
    }
  }
  float q0[QD], q1[QD];
  #pragma unroll
  for (int c = 0; c < QD; ++c) { q0[c] = (r == c) ? 1.f : 0.f; q1[c] = 0.f; }
  #pragma unroll
  for (int j = QD - 1; j >= 0; --j) {
    #pragma unroll
    for (int c = j; c < QD; ++c) {
      float p = v0[j] * q0[c] + v1[j] * q1[c];
      float s = wsum64(p) * tau[j];
      q0[c] -= s * v0[j];
      q1[c] -= s * v1[j];
    }
  }
  #pragma unroll
  for (int c = 0; c < QD; ++c) stg[r * QD + c] = q0[c];
  if (has1) {
    #pragma unroll
    for (int c = 0; c < QD; ++c) stg[(r + 64) * QD + c] = q1[c];
  }
  const float4* src = (const float4*)stg;
  float4* d4 = (float4*)dst;
  #pragma unroll
  for (int u = r; u < (D_OUT * QD) / 4; u += 64) d4[u] = src[u];
}

// ---------- fused: Y = W@X[b] (MFMA, W quarters + X both via global_load_lds),
//            then register-flat QR (panels staged to LDS first) ---------------
// amdgpu_waves_per_eu(4,4): PIN 4 waves/EU -> full 128-VGPR budget. With
// launch_bounds(256,4) the compiler's [4,8] range made it pick 64 VGPRs and
// spill ~19 MB (R7: WRITE 43 MB vs 32 ideal, VGPR_Count=64).
__global__ __launch_bounds__(256)
__attribute__((amdgpu_waves_per_eu(4, 4)))
void fused_kernel(const float* __restrict__ X,
                  const short* __restrict__ wfh,
                  const short* __restrict__ wfl,
                  float* __restrict__ out) {
  __shared__ __align__(16) float smem[SMEMF];   // [NW x 1280 X floats][2xQTR W shorts]
  const int tid  = threadIdx.x;
  const int lane = tid & 63;
  const int wv   = __builtin_amdgcn_readfirstlane(tid >> 6);
  const long b0  = (long)blockIdx.x * (NW * 2) + wv * 2;
  float* xs = smem + wv * XWF;
  short* wt = (short*)(smem + NW * XWF);
  const int col = lane & 15, quad = lane >> 4;

  f32x4 acc0[MTILES], acc1[MTILES];
  #pragma unroll
  for (int t = 0; t < MTILES; ++t) {
    acc0[t] = (f32x4){0.f, 0.f, 0.f, 0.f};
    acc1[t] = (f32x4){0.f, 0.f, 0.f, 0.f};
  }

  // W quarter load: 7 mt chunks over 4 waves, uniformly 2 gloads/wave.
  // wv0:{0,4} wv1:{1,5} wv2:{2,6} wv3:{3,6} (mt=6 duplicated: same data,
  // same LDS dst -> benign). vmcnt counts stay wave-uniform.
  auto wissue = [&](int kt, int ks, const short* pl, int buf) {
    const int m1 = wv;
    const int m2 = (wv < 3) ? wv + 4 : 6;
    gload_lds16(pl + ((long)(kt * MTILES + m1) * 2 + ks) * WCH + lane * 8,
                wt + buf * QTR + m1 * WCH);
    gload_lds16(pl + ((long)(kt * MTILES + m2) * 2 + ks) * WCH + lane * 8,
                wt + buf * QTR + m2 * WCH);
  };

  // X tile via global_load_lds: 320 float4 = 5 gloads x 64 lanes, contiguous
  // LDS dst [b0 640f | b1 640f]. kt=6 tail: lanes past the valid 40 float4
  // clamp src to tile start (finite garbage; k>=400 has W=0 -> exact 0).
  auto xissue = [&](int kt) {
    const int nk0 = kt * KT * QD;                 // float offset in batch
    const int vf4 = (kt == NKT - 1) ? 40 : 160;   // valid float4 per batch tile
    #pragma unroll
    for (int u = 0; u < 5; ++u) {
      const int idx = lane + u * 64;
      const int bsel = idx >= 160 ? 1 : 0;
      int within = idx - bsel * 160;
      if (within >= vf4) within = 0;
      gload_lds16(X + (b0 + bsel) * (long)(D_IN * QD) + nk0 + within * 4,
                  (char*)xs + u * 1024);
    }
  };

  bf16x8 b0h, b0l, b1h, b1l;
  auto buildFrags = [&](int ks) {
    #pragma unroll
    for (int m = 0; m < 8; ++m) {
      const int fo = (ks * 32 + quad * 8 + m) * QD + col;
      float x0 = xs[fo];
      float x1 = xs[640 + fo];
      __bf16 h0 = (__bf16)x0; float f0 = (float)h0; __bf16 g0 = (__bf16)(x0 - f0);
      __bf16 h1 = (__bf16)x1; float f1 = (float)h1; __bf16 g1 = (__bf16)(x1 - f1);
      b0h[m] = __builtin_bit_cast(short, h0); b0l[m] = __builtin_bit_cast(short, g0);
      b1h[m] = __builtin_bit_cast(short, h1); b1l[m] = __builtin_bit_cast(short, g1);
    }
  };
  auto computeHi = [&](int buf) {   // hi-plane A: ah*bh + ah*bl, both batches
    #pragma unroll
    for (int mt = 0; mt < MTILES; ++mt) {
      bf16x8 ah = *(const bf16x8*)(wt + buf * QTR + mt * WCH + lane * 8);
      acc0[mt] = __builtin_amdgcn_mfma_f32_16x16x32_bf16(ah, b0h, acc0[mt], 0, 0, 0);
      acc0[mt] = __builtin_amdgcn_mfma_f32_16x16x32_bf16(ah, b0l, acc0[mt], 0, 0, 0);
      acc1[mt] = __builtin_amdgcn_mfma_f32_16x16x32_bf16(ah, b1h, acc1[mt], 0, 0, 0);
      acc1[mt] = __builtin_amdgcn_mfma_f32_16x16x32_bf16(ah, b1l, acc1[mt], 0, 0, 0);
    }
  };
  auto computeLo = [&](int buf) {   // lo-plane A: al*bh, both batches
    #pragma unroll
    for (int mt = 0; mt < MTILES; ++mt) {
      bf16x8 al = *(const bf16x8*)(wt + buf * QTR + mt * WCH + lane * 8);
      acc0[mt] = __builtin_amdgcn_mfma_f32_16x16x32_bf16(al, b0h, acc0[mt], 0, 0, 0);
      acc1[mt] = __builtin_amdgcn_mfma_f32_16x16x32_bf16(al, b1h, acc1[mt], 0, 0, 0);
    }
  };

  // ---- prologue: queue = [W2, X5]; wait W (vmcnt(5)), X stays in flight ----
  wissue(0, 0, wfh, 0);
  __builtin_amdgcn_sched_barrier(0);
  xissue(0);
  __builtin_amdgcn_sched_barrier(0);
  asm volatile("s_waitcnt vmcnt(5)" ::: "memory");
  __builtin_amdgcn_s_barrier();
  __builtin_amdgcn_sched_barrier(0);

  #pragma unroll 1
  for (int kt = 0; kt < NKT; ++kt) {
    // q0: wait X(kt) (own-wave, vmcnt(2) leaves new W flying); compute ks0-hi.
    wissue(kt, 0, wfl, 1);
    __builtin_amdgcn_sched_barrier(0);
    asm volatile("s_waitcnt vmcnt(2)" ::: "memory");
    __builtin_amdgcn_sched_barrier(0);
    buildFrags(0);
    computeHi(0);
    asm volatile("s_waitcnt vmcnt(0)" ::: "memory");
    __builtin_amdgcn_s_barrier();
    __builtin_amdgcn_sched_barrier(0);
    // q1: compute ks0-lo from buf1; prefetch ks1-hi -> buf0.
    wissue(kt, 1, wfh, 0);
    computeLo(1);
    asm volatile("s_waitcnt vmcnt(0)" ::: "memory");
    __builtin_amdgcn_s_barrier();
    __builtin_amdgcn_sched_barrier(0);
    // q2: compute ks1-hi from buf0; prefetch ks1-lo -> buf1. Last xs read.
    wissue(kt, 1, wfl, 1);
    buildFrags(1);
    computeHi(0);
    asm volatile("s_waitcnt vmcnt(0)" ::: "memory");
    __builtin_amdgcn_s_barrier();
    __builtin_amdgcn_sched_barrier(0);
    // q3: compute ks1-lo from buf1; prefetch (kt+1,ks0,hi)->buf0 and X(kt+1).
    if (kt + 1 < NKT) {
      wissue(kt + 1, 0, wfh, 0);
      __builtin_amdgcn_sched_barrier(0);
      xissue(kt + 1);
      __builtin_amdgcn_sched_barrier(0);
    }
    computeLo(1);
    if (kt + 1 < NKT)
      asm volatile("s_waitcnt vmcnt(5)" ::: "memory");  // W done, X flying
    else
      asm volatile("s_waitcnt vmcnt(0)" ::: "memory");
    __builtin_amdgcn_s_barrier();   // final iter: doubles as pre-QR barrier
    __builtin_amdgcn_sched_barrier(0);
  }

  // ---- QR: dump BOTH acc panels to LDS first (acc dies -> flat reg peak),
  //      then two self-contained QRs. smem re-carved 4 x 2176 floats/wave. ----
  float* stgA = smem + wv * QRSTR;
  float* stgB = stgA + 1024;
  stage_panel(acc0, stgA, col, quad);
  stage_panel(acc1, stgB, col, quad);
  __builtin_amdgcn_sched_barrier(0);
  qr_from_stg(stgA, out + b0 * (long)(D_OUT * QD), lane);
  __builtin_amdgcn_sched_barrier(0);
  qr_from_stg(stgB, out + (b0 + 1) * (long)(D_OUT * QD), lane);
}

extern "C" void kernel_launch(void* const* d_in, const int* in_sizes, int n_in,
                              void* d_out, int out_size, void* d_ws, size_t ws_size,
                              hipStream_t stream) {
  const float* X = (const float*)d_in[0];   // (8192, 400, 10) fp32
  const float* W = (const float*)d_in[1];   // (100, 400) fp32
  float* out = (float*)d_out;               // (8192, 100, 10) fp32
  short* wfh = (short*)d_ws;                // 50176 shorts
  short* wfl = wfh + WFSZ;                  // 50176 shorts
  hipLaunchKernelGGL(wprep_kernel, dim3((WFSZ + 255) / 256), dim3(256), 0, stream,
                     W, wfh, wfl);
  hipLaunchKernelGGL(fused_kernel, dim3(BATCHES / (NW * 2)), dim3(256), 0, stream,
                     X, wfh, wfl, out);
}

// Round 9
// 222.039 us; speedup vs baseline: 1.0481x; 1.0481x over previous
//
#include <hip/hip_runtime.h>
#include <math.h>

#define BATCHES 8192
#define D_IN    400
#define D_OUT   100
#define QD      10
#define KT      64
#define NKT     7                              // 7*64 = 448 >= 400
#define MTILES  7                              // 7*16 = 112 >= 100
#define WFSZ    (NKT * MTILES * 2 * 64 * 8)    // 50176 shorts per plane
#define NW      4                              // waves per block, 2 batches per wave
#define WCH     512                            // shorts per W chunk (64 lanes x 8)
#define QTR     (7 * WCH)                      // 3584 shorts: one plane-quarter
#define XWF     1280                           // floats per wave X region (2 x 640)
#define SMEMF   (NW * XWF + QTR)               // 5120 + 3584 = 8704 floats = 34816 B
#define QRSTR   2176                           // floats per wave in QR carve (4x2176=8704)

using bf16x8 = __attribute__((ext_vector_type(8))) short;
using f32x4  = __attribute__((ext_vector_type(4))) float;

// ---- wave-64 sum via DPP (row_shr + row_bcast), result broadcast via SGPR ----
template <int CTRL>
__device__ __forceinline__ float dpp_add(float x) {
  int s = __builtin_amdgcn_update_dpp(0, __builtin_bit_cast(int, x),
                                      CTRL, 0xF, 0xF, true);
  return x + __builtin_bit_cast(float, s);
}

__device__ __forceinline__ float wsum64(float x) {
  x = dpp_add<0x111>(x);   // row_shr:1
  x = dpp_add<0x112>(x);   // row_shr:2
  x = dpp_add<0x114>(x);   // row_shr:4
  x = dpp_add<0x118>(x);   // row_shr:8
  x = dpp_add<0x142>(x);   // row_bcast:15
  x = dpp_add<0x143>(x);   // row_bcast:31 -> lane63 has total
  return __builtin_bit_cast(float,
      __builtin_amdgcn_readlane(__builtin_bit_cast(int, x), 63));
}

__device__ __forceinline__ float lane_bcast(float x, int lane) {
  return __builtin_bit_cast(float,
      __builtin_amdgcn_readlane(__builtin_bit_cast(int, x), lane));
}

// async global->LDS, 16B per lane: per-lane global src, wave-uniform LDS base
__device__ __forceinline__ void gload_lds16(const void* g, void* l) {
  __builtin_amdgcn_global_load_lds(
      (const __attribute__((address_space(1))) void*)g,
      (__attribute__((address_space(3))) void*)l, 16, 0, 0);
}

// ---------- prep: W (100,400) fp32 -> A-fragment-ordered bf16 hi/lo planes ----
// layout: e = (((kt*7+mt)*2+ks)*64 + lane)*8 + j ; lane = quad*16 + row16
// padded entries (o>=100 or k>=400) written as ZERO (k-pad MUST be zero: the
// fused kernel feeds garbage-but-finite X at padded k and relies on W=0).
__global__ __launch_bounds__(256) void wprep_kernel(const float* __restrict__ W,
                                                    short* __restrict__ wfh,
                                                    short* __restrict__ wfl) {
  const int e = blockIdx.x * 256 + threadIdx.x;
  if (e >= WFSZ) return;
  const int j = e & 7, lane = (e >> 3) & 63, ks = (e >> 9) & 1, mtkt = e >> 10;
  const int kt = mtkt / MTILES, mt = mtkt - kt * MTILES;
  const int o = mt * 16 + (lane & 15);
  const int k = kt * KT + ks * 32 + (lane >> 4) * 8 + j;
  const float w = (o < D_OUT && k < D_IN) ? W[o * D_IN + k] : 0.f;
  __bf16 h = (__bf16)w;
  float hf = (float)h;
  __bf16 l = (__bf16)(w - hf);
  wfh[e] = __builtin_bit_cast(short, h);
  wfl[e] = __builtin_bit_cast(short, l);
}

// ---------- QR pieces (LAPACK sgeqrf convention), rcp-based, wave-private ----
__device__ __forceinline__ void stage_panel(const f32x4* acc, float* stg,
                                            int col, int quad) {
  if (col < QD) {
    #pragma unroll
    for (int mt = 0; mt < MTILES; ++mt)
      #pragma unroll
      for (int rr = 0; rr < 4; ++rr) {
        const int o = mt * 16 + quad * 4 + rr;
        if (o < D_OUT) stg[o * QD + col] = acc[mt][rr];
      }
  }
}

__device__ __forceinline__ void qr_from_stg(float* stg, float* dst, int lane) {
  const int r = lane;
  float a0[QD], a1[QD];
  #pragma unroll
  for (int q = 0; q < QD; ++q) a0[q] = stg[r * QD + q];
  const bool has1 = (r + 64) < D_OUT;
  #pragma unroll
  for (int q = 0; q < QD; ++q) a1[q] = has1 ? stg[(r + 64) * QD + q] : 0.f;

  float v0[QD], v1[QD], tau[QD];
  #pragma unroll
  for (int j = 0; j < QD; ++j) {
    float cj0  = (r >= j) ? a0[j] : 0.f;
    float part = cj0 * cj0 + a1[j] * a1[j];
    float sig  = wsum64(part);
    float alpha = lane_bcast(a0[j], j);
    float nrm  = __builtin_amdgcn_sqrtf(sig);
    float aab  = fabsf(alpha);
    float rn   = __builtin_amdgcn_rcpf(nrm);
    float rd   = __builtin_amdgcn_rcpf(aab + nrm);
    float sgn  = (alpha >= 0.f) ? 1.f : -1.f;
    float tj   = (sig > 0.f) ? (1.f + aab * rn) : 0.f;
    float inv  = (sig > 0.f) ? sgn * rd : 0.f;      // 1/(alpha - beta)
    tau[j] = tj;
    v0[j]  = (r == j) ? 1.f : ((r > j) ? a0[j] * inv : 0.f);
    v1[j]  = a1[j] * inv;
    #pragma unroll
    for (int k = j + 1; k < QD; ++k) {
      float p = v0[j] * a0[k] + v1[j] * a1[k];
      float s = wsum64(p) * tj;
      a0[k] -= s * v0[j];
      a1[k] -= s * v1[j];
    }
  }
  float q0[QD], q1[QD];
  #pragma unroll
  for (int c = 0; c < QD; ++c) { q0[c] = (r == c) ? 1.f : 0.f; q1[c] = 0.f; }
  #pragma unroll
  for (int j = QD - 1; j >= 0; --j) {
    #pragma unroll
    for (int c = j; c < QD; ++c) {
      float p = v0[j] * q0[c] + v1[j] * q1[c];
      float s = wsum64(p) * tau[j];
      q0[c] -= s * v0[j];
      q1[c] -= s * v1[j];
    }
  }
  #pragma unroll
  for (int c = 0; c < QD; ++c) stg[r * QD + c] = q0[c];
  if (has1) {
    #pragma unroll
    for (int c = 0; c < QD; ++c) stg[(r + 64) * QD + c] = q1[c];
  }
  const float4* src = (const float4*)stg;
  float4* d4 = (float4*)dst;
  #pragma unroll
  for (int u = r; u < (D_OUT * QD) / 4; u += 64) d4[u] = src[u];
}

// ---------- fused: Y = W@X[b] (MFMA, W quarters + X both via global_load_lds),
//            then register-flat QR (panels staged to LDS first) ---------------
// launch_bounds(256,3): empirically the allocator gives ~80-112 VGPRs (R5:
// 80, zero spill). min=4 or waves_per_eu(4,4) both squeezed to 64 VGPRs and
// spilled ~11-65 MB (R4/R7/R8). At VGPR<=128 HW still allows 4 waves/EU, so
// the 34816 B LDS footprint keeps 4 blocks/CU resident -> single full round.
__global__ __launch_bounds__(256, 3)
void fused_kernel(const float* __restrict__ X,
                  const short* __restrict__ wfh,
                  const short* __restrict__ wfl,
                  float* __restrict__ out) {
  __shared__ __align__(16) float smem[SMEMF];   // [NW x 1280 X floats][2xQTR W shorts]
  const int tid  = threadIdx.x;
  const int lane = tid & 63;
  const int wv   = __builtin_amdgcn_readfirstlane(tid >> 6);
  const long b0  = (long)blockIdx.x * (NW * 2) + wv * 2;
  float* xs = smem + wv * XWF;
  short* wt = (short*)(smem + NW * XWF);
  const int col = lane & 15, quad = lane >> 4;

  f32x4 acc0[MTILES], acc1[MTILES];
  #pragma unroll
  for (int t = 0; t < MTILES; ++t) {
    acc0[t] = (f32x4){0.f, 0.f, 0.f, 0.f};
    acc1[t] = (f32x4){0.f, 0.f, 0.f, 0.f};
  }

  // W quarter load: 7 mt chunks over 4 waves, uniformly 2 gloads/wave.
  // wv0:{0,4} wv1:{1,5} wv2:{2,6} wv3:{3,6} (mt=6 duplicated: same data,
  // same LDS dst -> benign). vmcnt counts stay wave-uniform.
  auto wissue = [&](int kt, int ks, const short* pl, int buf) {
    const int m1 = wv;
    const int m2 = (wv < 3) ? wv + 4 : 6;
    gload_lds16(pl + ((long)(kt * MTILES + m1) * 2 + ks) * WCH + lane * 8,
                wt + buf * QTR + m1 * WCH);
    gload_lds16(pl + ((long)(kt * MTILES + m2) * 2 + ks) * WCH + lane * 8,
                wt + buf * QTR + m2 * WCH);
  };

  // X tile via global_load_lds: 320 float4 = 5 gloads x 64 lanes, contiguous
  // LDS dst [b0 640f | b1 640f]. kt=6 tail: lanes past the valid 40 float4
  // clamp src to tile start (finite garbage; k>=400 has W=0 -> exact 0).
  auto xissue = [&](int kt) {
    const int nk0 = kt * KT * QD;                 // float offset in batch
    const int vf4 = (kt == NKT - 1) ? 40 : 160;   // valid float4 per batch tile
    #pragma unroll
    for (int u = 0; u < 5; ++u) {
      const int idx = lane + u * 64;
      const int bsel = idx >= 160 ? 1 : 0;
      int within = idx - bsel * 160;
      if (within >= vf4) within = 0;
      gload_lds16(X + (b0 + bsel) * (long)(D_IN * QD) + nk0 + within * 4,
                  (char*)xs + u * 1024);
    }
  };

  bf16x8 b0h, b0l, b1h, b1l;
  auto buildFrags = [&](int ks) {
    #pragma unroll
    for (int m = 0; m < 8; ++m) {
      const int fo = (ks * 32 + quad * 8 + m) * QD + col;
      float x0 = xs[fo];
      float x1 = xs[640 + fo];
      __bf16 h0 = (__bf16)x0; float f0 = (float)h0; __bf16 g0 = (__bf16)(x0 - f0);
      __bf16 h1 = (__bf16)x1; float f1 = (float)h1; __bf16 g1 = (__bf16)(x1 - f1);
      b0h[m] = __builtin_bit_cast(short, h0); b0l[m] = __builtin_bit_cast(short, g0);
      b1h[m] = __builtin_bit_cast(short, h1); b1l[m] = __builtin_bit_cast(short, g1);
    }
  };
  auto computeHi = [&](int buf) {   // hi-plane A: ah*bh + ah*bl, both batches
    #pragma unroll
    for (int mt = 0; mt < MTILES; ++mt) {
      bf16x8 ah = *(const bf16x8*)(wt + buf * QTR + mt * WCH + lane * 8);
      acc0[mt] = __builtin_amdgcn_mfma_f32_16x16x32_bf16(ah, b0h, acc0[mt], 0, 0, 0);
      acc0[mt] = __builtin_amdgcn_mfma_f32_16x16x32_bf16(ah, b0l, acc0[mt], 0, 0, 0);
      acc1[mt] = __builtin_amdgcn_mfma_f32_16x16x32_bf16(ah, b1h, acc1[mt], 0, 0, 0);
      acc1[mt] = __builtin_amdgcn_mfma_f32_16x16x32_bf16(ah, b1l, acc1[mt], 0, 0, 0);
    }
  };
  auto computeLo = [&](int buf) {   // lo-plane A: al*bh, both batches
    #pragma unroll
    for (int mt = 0; mt < MTILES; ++mt) {
      bf16x8 al = *(const bf16x8*)(wt + buf * QTR + mt * WCH + lane * 8);
      acc0[mt] = __builtin_amdgcn_mfma_f32_16x16x32_bf16(al, b0h, acc0[mt], 0, 0, 0);
      acc1[mt] = __builtin_amdgcn_mfma_f32_16x16x32_bf16(al, b1h, acc1[mt], 0, 0, 0);
    }
  };

  // ---- prologue: queue = [W2, X5]; wait W (vmcnt(5)), X stays in flight ----
  wissue(0, 0, wfh, 0);
  __builtin_amdgcn_sched_barrier(0);
  xissue(0);
  __builtin_amdgcn_sched_barrier(0);
  asm volatile("s_waitcnt vmcnt(5)" ::: "memory");
  __builtin_amdgcn_s_barrier();
  __builtin_amdgcn_sched_barrier(0);

  #pragma unroll 1
  for (int kt = 0; kt < NKT; ++kt) {
    // q0: wait X(kt) (own-wave, vmcnt(2) leaves new W flying); compute ks0-hi.
    wissue(kt, 0, wfl, 1);
    __builtin_amdgcn_sched_barrier(0);
    asm volatile("s_waitcnt vmcnt(2)" ::: "memory");
    __builtin_amdgcn_sched_barrier(0);
    buildFrags(0);
    computeHi(0);
    asm volatile("s_waitcnt vmcnt(0)" ::: "memory");
    __builtin_amdgcn_s_barrier();
    __builtin_amdgcn_sched_barrier(0);
    // q1: compute ks0-lo from buf1; prefetch ks1-hi -> buf0.
    wissue(kt, 1, wfh, 0);
    computeLo(1);
    asm volatile("s_waitcnt vmcnt(0)" ::: "memory");
    __builtin_amdgcn_s_barrier();
    __builtin_amdgcn_sched_barrier(0);
    // q2: compute ks1-hi from buf0; prefetch ks1-lo -> buf1. Last xs read.
    wissue(kt, 1, wfl, 1);
    buildFrags(1);
    computeHi(0);
    asm volatile("s_waitcnt vmcnt(0)" ::: "memory");
    __builtin_amdgcn_s_barrier();
    __builtin_amdgcn_sched_barrier(0);
    // q3: compute ks1-lo from buf1; prefetch (kt+1,ks0,hi)->buf0 and X(kt+1).
    if (kt + 1 < NKT) {
      wissue(kt + 1, 0, wfh, 0);
      __builtin_amdgcn_sched_barrier(0);
      xissue(kt + 1);
      __builtin_amdgcn_sched_barrier(0);
    }
    computeLo(1);
    if (kt + 1 < NKT)
      asm volatile("s_waitcnt vmcnt(5)" ::: "memory");  // W done, X flying
    else
      asm volatile("s_waitcnt vmcnt(0)" ::: "memory");
    __builtin_amdgcn_s_barrier();   // final iter: doubles as pre-QR barrier
    __builtin_amdgcn_sched_barrier(0);
  }

  // ---- QR: dump BOTH acc panels to LDS first (acc dies -> flat reg peak),
  //      then two self-contained QRs. smem re-carved 4 x 2176 floats/wave. ----
  float* stgA = smem + wv * QRSTR;
  float* stgB = stgA + 1024;
  stage_panel(acc0, stgA, col, quad);
  stage_panel(acc1, stgB, col, quad);
  __builtin_amdgcn_sched_barrier(0);
  qr_from_stg(stgA, out + b0 * (long)(D_OUT * QD), lane);
  __builtin_amdgcn_sched_barrier(0);
  qr_from_stg(stgB, out + (b0 + 1) * (long)(D_OUT * QD), lane);
}

extern "C" void kernel_launch(void* const* d_in, const int* in_sizes, int n_in,
                              void* d_out, int out_size, void* d_ws, size_t ws_size,
                              hipStream_t stream) {
  const float* X = (const float*)d_in[0];   // (8192, 400, 10) fp32
  const float* W = (const float*)d_in[1];   // (100, 400) fp32
  float* out = (float*)d_out;               // (8192, 100, 10) fp32
  short* wfh = (short*)d_ws;                // 50176 shorts
  short* wfl = wfh + WFSZ;                  // 50176 shorts
  hipLaunchKernelGGL(wprep_kernel, dim3((WFSZ + 255) / 256), dim3(256), 0, stream,
                     W, wfh, wfl);
  hipLaunchKernelGGL(fused_kernel, dim3(BATCHES / (NW * 2)), dim3(256), 0, stream,
                     X, wfh, wfl, out);
}